// Round 1
// baseline (1264.072 us; speedup 1.0000x reference)
//
#include <hip/hip_runtime.h>
#include <stdint.h>

#define E_TOTAL 640000
#define EPS_LN 1e-5f

typedef short s16x8 __attribute__((ext_vector_type(8)));
typedef float f32x4 __attribute__((ext_vector_type(4)));

// f32 -> bf16 round-to-nearest-even (prep only)
__device__ __forceinline__ short bfr(float f) {
    uint32_t u = __builtin_bit_cast(uint32_t, f);
    u += 0x7fffu + ((u >> 16) & 1u);
    return (short)(u >> 16);
}

// packed f32 pair -> bf16 pair (lo -> low 16 bits)
__device__ __forceinline__ uint32_t cvtpk(float lo, float hi) {
    uint32_t r;
    asm("v_cvt_pk_bf16_f32 %0, %1, %2" : "=v"(r) : "v"(lo), "v"(hi));
    return r;
}

__device__ __forceinline__ s16x8 pack8(uint32_t a, uint32_t b, uint32_t c, uint32_t d) {
    union { uint32_t u[4]; s16x8 v; } r;
    r.u[0] = a; r.u[1] = b; r.u[2] = c; r.u[3] = d;
    return r.v;
}

__device__ __forceinline__ s16x8 cvt8pk(f32x4 x, f32x4 y) {
    return pack8(cvtpk(x[0], x[1]), cvtpk(x[2], x[3]),
                 cvtpk(y[0], y[1]), cvtpk(y[2], y[3]));
}

#define MFMA(w, x, c) __builtin_amdgcn_mfma_f32_16x16x32_bf16((w), (x), (c), 0, 0, 0)

// ---------------------------------------------------------------------------
// Prep: W -> bf16 MFMA A-fragment order (weights are operand A now).
// Flat: [((u*(K/32) + ks)*64 + lane)*8 + j]
//   W1 (identity k-slots): k = ks*32 + q*8 + j            (same layout as before)
//   W2/W3 (sigma-permuted): k = ks*32 + (j<4 ? q*4+j : 16 + q*4 + j-4)
// so that layer-(i+1) B-fragments are pure register repacks of layer-i acc.
// ---------------------------------------------------------------------------
__global__ void prep_weights(const float* __restrict__ W1,
                             const float* __restrict__ W2,
                             const float* __restrict__ W3,
                             short* __restrict__ wt) {
    int i = blockIdx.x * 256 + threadIdx.x;   // grid: 768*256 = 196608 exact
    const float* W;
    int K, N, base, perm, idx = i;
    if (idx < 98304)       { W = W1; K = 384; N = 256; base = 0;      perm = 0; }
    else if (idx < 163840) { W = W2; K = 256; N = 256; base = 98304;  perm = 1; idx -= 98304; }
    else                   { W = W3; K = 256; N = 128; base = 163840; perm = 1; idx -= 163840; }
    int j    = idx & 7;
    int lane = (idx >> 3) & 63;
    int rest = idx >> 9;
    int nk   = K / 32;
    int ks   = rest % nk;
    int u    = rest / nk;
    int q    = lane >> 4;
    int kin  = perm ? ((j < 4) ? (q * 4 + j) : (16 + q * 4 + (j - 4)))
                    : (q * 8 + j);
    int k = ks * 32 + kin;
    int n = u * 16 + (lane & 15);
    wt[base + idx] = bfr(W[k * N + n]);
}

// ---------------------------------------------------------------------------
// Fused edge MLP + LayerNorm, operand-swapped MFMA (h^T = W^T @ X^T):
// C-layout keeps edge on lane&15 and channels in-register for ALL layers,
// so no LDS transpose round trip exists. 4 waves/block, 32 edges/wave.
// ---------------------------------------------------------------------------
__global__ __launch_bounds__(256, 2)
void edge_mlp(const float* __restrict__ node_feat,
              const float* __restrict__ edge_feat,
              const int*   __restrict__ eidx,
              const short* __restrict__ wt,
              const float* __restrict__ b1,
              const float* __restrict__ b2,
              const float* __restrict__ b3,
              const float* __restrict__ gamma,
              const float* __restrict__ beta,
              float* __restrict__ out) {
    const int tid  = threadIdx.x;
    const int lane = tid & 63;
    const int wave = tid >> 6;
    const int q    = lane >> 4;
    const int l15  = lane & 15;
    const int m_base = blockIdx.x * 128 + wave * 32;

    // each lane supplies B-fragments (and receives outputs) for edges e0, e1
    const int e0 = m_base + l15;
    const int e1 = e0 + 16;
    const int s0 = eidx[e0],           s1 = eidx[e1];
    const int d0 = eidx[E_TOTAL + e0], d1 = eidx[E_TOTAL + e1];

    const float* xa0[3] = { node_feat + (size_t)s0 * 128,
                            node_feat + (size_t)d0 * 128,
                            edge_feat + (size_t)e0 * 128 };
    const float* xa1[3] = { node_feat + (size_t)s1 * 128,
                            node_feat + (size_t)d1 * 128,
                            edge_feat + (size_t)e1 * 128 };

    const short* w1 = wt;
    const short* w2 = wt + 98304;
    const short* w3 = wt + 163840;

    f32x4 acc[2][16];
    f32x4 st[2][2][2];   // [buf][t][half] gather staging, depth-2 prefetch

#define LDX(buf, kk) { \
    const float* p0_ = xa0[(kk) >> 2] + ((kk) & 3) * 32 + q * 8; \
    const float* p1_ = xa1[(kk) >> 2] + ((kk) & 3) * 32 + q * 8; \
    st[buf][0][0] = *(const f32x4*)p0_; st[buf][0][1] = *(const f32x4*)(p0_ + 4); \
    st[buf][1][0] = *(const f32x4*)p1_; st[buf][1][1] = *(const f32x4*)(p1_ + 4); }

    LDX(0, 0)
    LDX(1, 1)

    // ================= layer 1: h1^T = W1^T @ X^T, +b1 =====================
    #pragma unroll
    for (int u = 0; u < 16; ++u) {
        f32x4 bv = *(const f32x4*)(b1 + u * 16 + q * 4);
        acc[0][u] = bv; acc[1][u] = bv;
    }
    #pragma unroll
    for (int ks = 0; ks < 12; ++ks) {
        s16x8 xb0 = cvt8pk(st[ks & 1][0][0], st[ks & 1][0][1]);
        s16x8 xb1 = cvt8pk(st[ks & 1][1][0], st[ks & 1][1][1]);
        if (ks < 10) LDX(ks & 1, ks + 2)            // prefetch 2 chunks ahead
        const short* wb = w1 + ks * 512 + lane * 8; // u-stride = 12*64*8 = 6144
        __builtin_amdgcn_s_setprio(1);
        #pragma unroll
        for (int u = 0; u < 16; ++u) {
            s16x8 wf = *(const s16x8*)(wb + u * 6144);
            acc[0][u] = MFMA(wf, xb0, acc[0][u]);
            acc[1][u] = MFMA(wf, xb1, acc[1][u]);
        }
        __builtin_amdgcn_s_setprio(0);
    }

    // relu + cvt -> layer-2 B-fragments, pure in-register repack (sigma slots)
    s16x8 hbf[2][8];
    #pragma unroll
    for (int t = 0; t < 2; ++t)
        #pragma unroll
        for (int m = 0; m < 8; ++m) {
            f32x4 a0 = acc[t][2 * m], a1 = acc[t][2 * m + 1];
            hbf[t][m] = pack8(cvtpk(fmaxf(a0[0], 0.f), fmaxf(a0[1], 0.f)),
                              cvtpk(fmaxf(a0[2], 0.f), fmaxf(a0[3], 0.f)),
                              cvtpk(fmaxf(a1[0], 0.f), fmaxf(a1[1], 0.f)),
                              cvtpk(fmaxf(a1[2], 0.f), fmaxf(a1[3], 0.f)));
        }

    // ================= layer 2: h2^T = W2^T @ h1^T, +b2 ====================
    #pragma unroll
    for (int u = 0; u < 16; ++u) {
        f32x4 bv = *(const f32x4*)(b2 + u * 16 + q * 4);
        acc[0][u] = bv; acc[1][u] = bv;
    }
    #pragma unroll
    for (int ks = 0; ks < 8; ++ks) {
        const short* wb = w2 + ks * 512 + lane * 8; // u-stride = 8*64*8 = 4096
        s16x8 xb0 = hbf[0][ks], xb1 = hbf[1][ks];
        __builtin_amdgcn_s_setprio(1);
        #pragma unroll
        for (int u = 0; u < 16; ++u) {
            s16x8 wf = *(const s16x8*)(wb + u * 4096);
            acc[0][u] = MFMA(wf, xb0, acc[0][u]);
            acc[1][u] = MFMA(wf, xb1, acc[1][u]);
        }
        __builtin_amdgcn_s_setprio(0);
    }

    // relu + cvt -> layer-3 B-fragments (reuse hbf)
    #pragma unroll
    for (int t = 0; t < 2; ++t)
        #pragma unroll
        for (int m = 0; m < 8; ++m) {
            f32x4 a0 = acc[t][2 * m], a1 = acc[t][2 * m + 1];
            hbf[t][m] = pack8(cvtpk(fmaxf(a0[0], 0.f), fmaxf(a0[1], 0.f)),
                              cvtpk(fmaxf(a0[2], 0.f), fmaxf(a0[3], 0.f)),
                              cvtpk(fmaxf(a1[0], 0.f), fmaxf(a1[1], 0.f)),
                              cvtpk(fmaxf(a1[2], 0.f), fmaxf(a1[3], 0.f)));
        }

    // ================= layer 3: h3^T = W3^T @ h2^T, +b3 ====================
    #pragma unroll
    for (int u = 0; u < 8; ++u) {
        f32x4 bv = *(const f32x4*)(b3 + u * 16 + q * 4);
        acc[0][u] = bv; acc[1][u] = bv;
    }
    #pragma unroll
    for (int ks = 0; ks < 8; ++ks) {
        const short* wb = w3 + ks * 512 + lane * 8; // u-stride = 8*64*8 = 4096
        s16x8 xb0 = hbf[0][ks], xb1 = hbf[1][ks];
        __builtin_amdgcn_s_setprio(1);
        #pragma unroll
        for (int u = 0; u < 8; ++u) {
            s16x8 wf = *(const s16x8*)(wb + u * 4096);
            acc[0][u] = MFMA(wf, xb0, acc[0][u]);
            acc[1][u] = MFMA(wf, xb1, acc[1][u]);
        }
        __builtin_amdgcn_s_setprio(0);
    }

    // ================= LayerNorm(128) + store ==============================
    // lane holds 32 of edge(t,l15)'s 128 channels; quads q=0..3 hold the rest
    f32x4 g[8], be[8];
    #pragma unroll
    for (int u = 0; u < 8; ++u) {
        g[u]  = *(const f32x4*)(gamma + u * 16 + q * 4);
        be[u] = *(const f32x4*)(beta  + u * 16 + q * 4);
    }
    #pragma unroll
    for (int t = 0; t < 2; ++t) {
        float s = 0.f, ss = 0.f;
        #pragma unroll
        for (int u = 0; u < 8; ++u)
            #pragma unroll
            for (int r = 0; r < 4; ++r) {
                float v = acc[t][u][r];
                s += v; ss += v * v;
            }
        s  += __shfl_xor(s, 16, 64);  s  += __shfl_xor(s, 32, 64);
        ss += __shfl_xor(ss, 16, 64); ss += __shfl_xor(ss, 32, 64);
        float mu  = s * (1.0f / 128.0f);
        float var = ss * (1.0f / 128.0f) - mu * mu;
        float inv = rsqrtf(var + EPS_LN);
        float* orow = out + (size_t)(m_base + t * 16 + l15) * 128;
        #pragma unroll
        for (int u = 0; u < 8; ++u) {
            f32x4 o;
            #pragma unroll
            for (int r = 0; r < 4; ++r)
                o[r] = (acc[t][u][r] - mu) * inv * g[u][r] + be[u][r];
            *(f32x4*)(orow + u * 16 + q * 4) = o;
        }
    }
#undef LDX
}

extern "C" void kernel_launch(void* const* d_in, const int* in_sizes, int n_in,
                              void* d_out, int out_size, void* d_ws, size_t ws_size,
                              hipStream_t stream) {
    const float* node_feat = (const float*)d_in[0];
    const float* edge_feat = (const float*)d_in[1];
    const int*   eidx      = (const int*)  d_in[2];
    const float* W1        = (const float*)d_in[3];
    const float* b1        = (const float*)d_in[4];
    const float* W2        = (const float*)d_in[5];
    const float* b2        = (const float*)d_in[6];
    const float* W3        = (const float*)d_in[7];
    const float* b3        = (const float*)d_in[8];
    const float* gamma     = (const float*)d_in[9];
    const float* beta      = (const float*)d_in[10];
    float* out = (float*)d_out;
    short* wt  = (short*)d_ws;   // 196608 bf16 = 393216 bytes

    prep_weights<<<768, 256, 0, stream>>>(W1, W2, W3, wt);
    edge_mlp<<<E_TOTAL / 128, 256, 0, stream>>>(node_feat, edge_feat, eidx, wt,
                                                b1, b2, b3, gamma, beta, out);
}

// Round 3
// 737.821 us; speedup vs baseline: 1.7132x; 1.7132x over previous
//
#include <hip/hip_runtime.h>
#include <stdint.h>

#define E_TOTAL 640000
#define EPS_LN 1e-5f

typedef short s16x8 __attribute__((ext_vector_type(8)));
typedef float f32x4 __attribute__((ext_vector_type(4)));

// f32 -> bf16 round-to-nearest-even (prep only)
__device__ __forceinline__ short bfr(float f) {
    uint32_t u = __builtin_bit_cast(uint32_t, f);
    u += 0x7fffu + ((u >> 16) & 1u);
    return (short)(u >> 16);
}

// packed f32 pair -> bf16 pair (lo -> low 16 bits)
__device__ __forceinline__ uint32_t cvtpk(float lo, float hi) {
    uint32_t r;
    asm("v_cvt_pk_bf16_f32 %0, %1, %2" : "=v"(r) : "v"(lo), "v"(hi));
    return r;
}

__device__ __forceinline__ s16x8 pack8(uint32_t a, uint32_t b, uint32_t c, uint32_t d) {
    union { uint32_t u[4]; s16x8 v; } r;
    r.u[0] = a; r.u[1] = b; r.u[2] = c; r.u[3] = d;
    return r.v;
}

__device__ __forceinline__ s16x8 cvt8pk(f32x4 x, f32x4 y) {
    return pack8(cvtpk(x[0], x[1]), cvtpk(x[2], x[3]),
                 cvtpk(y[0], y[1]), cvtpk(y[2], y[3]));
}

// async global -> LDS, 16B per lane. lds dst = wave-uniform base + lane*16.
__device__ __forceinline__ void gload16(const short* g, short* l) {
    __builtin_amdgcn_global_load_lds(
        (const __attribute__((address_space(1))) void*)g,
        (__attribute__((address_space(3))) void*)l, 16, 0, 0);
}

#define MFMA(w, x, c) __builtin_amdgcn_mfma_f32_16x16x32_bf16((w), (x), (c), 0, 0, 0)

// ---------------------------------------------------------------------------
// Prep: W -> bf16 MFMA A-fragment order (weights are operand A).
// Flat: [((u*(K/32) + ks)*64 + lane)*8 + j]
//   W1 (identity k-slots): k = ks*32 + q*8 + j
//   W2/W3 (sigma-permuted): k = ks*32 + (j<4 ? q*4+j : 16 + q*4 + j-4)
// ---------------------------------------------------------------------------
__global__ void prep_weights(const float* __restrict__ W1,
                             const float* __restrict__ W2,
                             const float* __restrict__ W3,
                             short* __restrict__ wt) {
    int i = blockIdx.x * 256 + threadIdx.x;   // grid: 768*256 = 196608 exact
    const float* W;
    int K, N, base, perm, idx = i;
    if (idx < 98304)       { W = W1; K = 384; N = 256; base = 0;      perm = 0; }
    else if (idx < 163840) { W = W2; K = 256; N = 256; base = 98304;  perm = 1; idx -= 98304; }
    else                   { W = W3; K = 256; N = 128; base = 163840; perm = 1; idx -= 163840; }
    int j    = idx & 7;
    int lane = (idx >> 3) & 63;
    int rest = idx >> 9;
    int nk   = K / 32;
    int ks   = rest % nk;
    int u    = rest / nk;
    int q    = lane >> 4;
    int kin  = perm ? ((j < 4) ? (q * 4 + j) : (16 + q * 4 + (j - 4)))
                    : (q * 8 + j);
    int k = ks * 32 + kin;
    int n = u * 16 + (lane & 15);
    wt[base + idx] = bfr(W[k * N + n]);
}

// stage one 16|8 KiB weight chunk (NU u-slices of 1 KiB) into LDS, split
// across the block's 4 waves. Async; completed by the next __syncthreads().
template <int NK, int NU>
__device__ __forceinline__ void stage(short* dst, const short* w, int ks,
                                      int wave, int lane) {
    #pragma unroll
    for (int i = 0; i < NU / 4; ++i) {
        int u = wave * (NU / 4) + i;
        gload16(w + ((size_t)(u * NK + ks) * 64 + lane) * 8, dst + u * 512);
    }
}

// ---------------------------------------------------------------------------
// Fused edge MLP + LayerNorm, operand-swapped MFMA (h^T = W^T @ X^T).
// Weights double-buffered in LDS (block-cooperative, async staged);
// activations live entirely in registers between layers.
// ---------------------------------------------------------------------------
__global__ __launch_bounds__(256, 2)
void edge_mlp(const float* __restrict__ node_feat,
              const float* __restrict__ edge_feat,
              const int*   __restrict__ eidx,
              const short* __restrict__ wt,
              const float* __restrict__ b1,
              const float* __restrict__ b2,
              const float* __restrict__ b3,
              const float* __restrict__ gamma,
              const float* __restrict__ beta,
              float* __restrict__ out) {
    __shared__ __align__(16) short wbuf[2][8192];   // 2 x 16 KiB chunk buffers

    const int tid  = threadIdx.x;
    const int lane = tid & 63;
    const int wave = tid >> 6;
    const int q    = lane >> 4;
    const int l15  = lane & 15;
    const int m_base = blockIdx.x * 128 + wave * 32;

    const int e0 = m_base + l15;
    const int e1 = e0 + 16;
    const int s0 = eidx[e0],           s1 = eidx[e1];
    const int d0 = eidx[E_TOTAL + e0], d1 = eidx[E_TOTAL + e1];

    const float* xa0[3] = { node_feat + (size_t)s0 * 128,
                            node_feat + (size_t)d0 * 128,
                            edge_feat + (size_t)e0 * 128 };
    const float* xa1[3] = { node_feat + (size_t)s1 * 128,
                            node_feat + (size_t)d1 * 128,
                            edge_feat + (size_t)e1 * 128 };

    const short* w1 = wt;
    const short* w2 = wt + 98304;
    const short* w3 = wt + 163840;

    f32x4 acc[2][16];
    f32x4 st[2][2][2];   // [buf][t][half] gather staging, depth-2 prefetch

#define LDX(buf, kk) { \
    const float* p0_ = xa0[(kk) >> 2] + ((kk) & 3) * 32 + q * 8; \
    const float* p1_ = xa1[(kk) >> 2] + ((kk) & 3) * 32 + q * 8; \
    st[buf][0][0] = *(const f32x4*)p0_; st[buf][0][1] = *(const f32x4*)(p0_ + 4); \
    st[buf][1][0] = *(const f32x4*)p1_; st[buf][1][1] = *(const f32x4*)(p1_ + 4); }

    LDX(0, 0)
    LDX(1, 1)
    stage<12, 16>(wbuf[0], w1, 0, wave, lane);   // W1 chunk 0
    __syncthreads();                             // drains vmcnt: chunk0 + x ready

    // ================= layer 1: h1^T = W1^T @ X^T, +b1 =====================
    #pragma unroll
    for (int u = 0; u < 16; ++u) {
        f32x4 bv = *(const f32x4*)(b1 + u * 16 + q * 4);
        acc[0][u] = bv; acc[1][u] = bv;
    }
    #pragma unroll
    for (int ks = 0; ks < 12; ++ks) {
        // consume st[ks&1] FIRST (registers), then prefetch into that buffer
        s16x8 xb0 = cvt8pk(st[ks & 1][0][0], st[ks & 1][0][1]);
        s16x8 xb1 = cvt8pk(st[ks & 1][1][0], st[ks & 1][1][1]);
        if (ks < 11) stage<12, 16>(wbuf[(ks + 1) & 1], w1, ks + 1, wave, lane);
        else         stage<8, 16>(wbuf[0], w2, 0, wave, lane);  // global chunk 12
        if (ks < 10) LDX(ks & 1, ks + 2)
        const short* wb = wbuf[ks & 1] + lane * 8;
        __builtin_amdgcn_s_setprio(1);
        #pragma unroll
        for (int u = 0; u < 16; ++u) {
            s16x8 wf = *(const s16x8*)(wb + u * 512);
            acc[0][u] = MFMA(wf, xb0, acc[0][u]);
            acc[1][u] = MFMA(wf, xb1, acc[1][u]);
        }
        __builtin_amdgcn_s_setprio(0);
        __syncthreads();
    }

    // relu + cvt -> layer-2 B-fragments, pure in-register repack
    s16x8 hbf[2][8];
    #pragma unroll
    for (int t = 0; t < 2; ++t)
        #pragma unroll
        for (int m = 0; m < 8; ++m) {
            f32x4 a0 = acc[t][2 * m], a1 = acc[t][2 * m + 1];
            hbf[t][m] = pack8(cvtpk(fmaxf(a0[0], 0.f), fmaxf(a0[1], 0.f)),
                              cvtpk(fmaxf(a0[2], 0.f), fmaxf(a0[3], 0.f)),
                              cvtpk(fmaxf(a1[0], 0.f), fmaxf(a1[1], 0.f)),
                              cvtpk(fmaxf(a1[2], 0.f), fmaxf(a1[3], 0.f)));
        }

    // ================= layer 2: h2^T = W2^T @ h1^T, +b2 ====================
    #pragma unroll
    for (int u = 0; u < 16; ++u) {
        f32x4 bv = *(const f32x4*)(b2 + u * 16 + q * 4);
        acc[0][u] = bv; acc[1][u] = bv;
    }
    #pragma unroll
    for (int ks = 0; ks < 8; ++ks) {            // global chunks 12..19
        if (ks < 7) stage<8, 16>(wbuf[(ks + 1) & 1], w2, ks + 1, wave, lane);
        else        stage<8, 8>(wbuf[0], w3, 0, wave, lane);    // global chunk 20
        s16x8 xb0 = hbf[0][ks], xb1 = hbf[1][ks];
        const short* wb = wbuf[ks & 1] + lane * 8;
        __builtin_amdgcn_s_setprio(1);
        #pragma unroll
        for (int u = 0; u < 16; ++u) {
            s16x8 wf = *(const s16x8*)(wb + u * 512);
            acc[0][u] = MFMA(wf, xb0, acc[0][u]);
            acc[1][u] = MFMA(wf, xb1, acc[1][u]);
        }
        __builtin_amdgcn_s_setprio(0);
        __syncthreads();
    }

    // relu + cvt -> layer-3 B-fragments (reuse hbf)
    #pragma unroll
    for (int t = 0; t < 2; ++t)
        #pragma unroll
        for (int m = 0; m < 8; ++m) {
            f32x4 a0 = acc[t][2 * m], a1 = acc[t][2 * m + 1];
            hbf[t][m] = pack8(cvtpk(fmaxf(a0[0], 0.f), fmaxf(a0[1], 0.f)),
                              cvtpk(fmaxf(a0[2], 0.f), fmaxf(a0[3], 0.f)),
                              cvtpk(fmaxf(a1[0], 0.f), fmaxf(a1[1], 0.f)),
                              cvtpk(fmaxf(a1[2], 0.f), fmaxf(a1[3], 0.f)));
        }

    // ================= layer 3: h3^T = W3^T @ h2^T, +b3 ====================
    #pragma unroll
    for (int u = 0; u < 8; ++u) {
        f32x4 bv = *(const f32x4*)(b3 + u * 16 + q * 4);
        acc[0][u] = bv; acc[1][u] = bv;
    }
    #pragma unroll
    for (int ks = 0; ks < 8; ++ks) {            // global chunks 20..27
        if (ks < 7) stage<8, 8>(wbuf[(ks + 1) & 1], w3, ks + 1, wave, lane);
        s16x8 xb0 = hbf[0][ks], xb1 = hbf[1][ks];
        const short* wb = wbuf[ks & 1] + lane * 8;
        __builtin_amdgcn_s_setprio(1);
        #pragma unroll
        for (int u = 0; u < 8; ++u) {
            s16x8 wf = *(const s16x8*)(wb + u * 512);
            acc[0][u] = MFMA(wf, xb0, acc[0][u]);
            acc[1][u] = MFMA(wf, xb1, acc[1][u]);
        }
        __builtin_amdgcn_s_setprio(0);
        __syncthreads();   // final one also fences wbuf for epilogue reuse
    }

    // ================= LayerNorm(128) + transposed store ===================
    // lane (q,l15) holds cols u*16+q*4+r of edge row (m_base + t*16 + l15).
    // Stores via per-wave-private LDS slice so each store instr is 1 KiB dense.
    float* fw = reinterpret_cast<float*>(wbuf) + wave * 2048;   // 8 KiB slice

    f32x4 g[8], be[8];
    #pragma unroll
    for (int u = 0; u < 8; ++u) {
        g[u]  = *(const f32x4*)(gamma + u * 16 + q * 4);
        be[u] = *(const f32x4*)(beta  + u * 16 + q * 4);
    }
    #pragma unroll
    for (int t = 0; t < 2; ++t) {
        float s = 0.f, ss = 0.f;
        #pragma unroll
        for (int u = 0; u < 8; ++u)
            #pragma unroll
            for (int r = 0; r < 4; ++r) {
                float v = acc[t][u][r];
                s += v; ss += v * v;
            }
        s  += __shfl_xor(s, 16, 64);  s  += __shfl_xor(s, 32, 64);
        ss += __shfl_xor(ss, 16, 64); ss += __shfl_xor(ss, 32, 64);
        float mu  = s * (1.0f / 128.0f);
        float var = ss * (1.0f / 128.0f) - mu * mu;
        float inv = rsqrtf(var + EPS_LN);
        // normalized -> LDS (16B chunks, chunk idx XOR-swizzled by row&7)
        #pragma unroll
        for (int u = 0; u < 8; ++u) {
            f32x4 o = (acc[t][u] - mu) * inv * g[u] + be[u];
            *(f32x4*)(fw + l15 * 128 + (((u * 4 + q) ^ (l15 & 7)) << 2)) = o;
        }
        // read back row-major, store 2 full rows (1 KiB dense) per instr
        #pragma unroll
        for (int i = 0; i < 8; ++i) {
            int idx = i * 64 + lane;
            int r16 = idx >> 5;          // 0..15
            int c   = idx & 31;          // 16B chunk within row
            f32x4 v = *(const f32x4*)(fw + r16 * 128 + ((c ^ (r16 & 7)) << 2));
            *(f32x4*)(out + (size_t)(m_base + t * 16 + r16) * 128 + c * 4) = v;
        }
    }
#undef LDX
}

extern "C" void kernel_launch(void* const* d_in, const int* in_sizes, int n_in,
                              void* d_out, int out_size, void* d_ws, size_t ws_size,
                              hipStream_t stream) {
    const float* node_feat = (const float*)d_in[0];
    const float* edge_feat = (const float*)d_in[1];
    const int*   eidx      = (const int*)  d_in[2];
    const float* W1        = (const float*)d_in[3];
    const float* b1        = (const float*)d_in[4];
    const float* W2        = (const float*)d_in[5];
    const float* b2        = (const float*)d_in[6];
    const float* W3        = (const float*)d_in[7];
    const float* b3        = (const float*)d_in[8];
    const float* gamma     = (const float*)d_in[9];
    const float* beta      = (const float*)d_in[10];
    float* out = (float*)d_out;
    short* wt  = (short*)d_ws;   // 196608 bf16 = 393216 bytes

    prep_weights<<<768, 256, 0, stream>>>(W1, W2, W3, wt);
    edge_mlp<<<E_TOTAL / 128, 256, 0, stream>>>(node_feat, edge_feat, eidx, wt,
                                                b1, b2, b3, gamma, beta, out);
}